// Round 16
// baseline (753.540 us; speedup 1.0000x reference)
//
#include <hip/hip_runtime.h>
#include <hip/hip_fp16.h>

// VQ codebook argmin: N=32768 queries x K=8192 codes x D=256 fp32.
// f16 hi/lo split (3 MFMA terms) => fp32-accurate dots on the matrix pipe;
// fused running argmin. Scaling (exact powers of 2, argmin-invariant):
// z*=2^4, e*=2^15; dist_scaled = 2^19*cb_sq - 2*acc.
//
// R16: REGISTER-LEVEL B PREFETCH. R15 closed the prep arc (total-main
// ~= 10us prep + ~50us fixed). vq_main's VGPR_Count=96 under a 256-reg
// budget proves the compiler serialized all fragment traffic through
// ~24 regs -> per-kk L2 loads are exposed, the 37% MFMA idle. Fix:
// double-buffered B fragment sets (named, compile-time indexed), with
// LOADB(kk+1) issued BEFORE the MFMA block of kk. A stays single-set
// (LDS ~120cyc, sibling-covered). FP order bitwise identical to R15.
// Est. 212 regs < 256 @ 2 waves/SIMD. Kill-criterion: WRITE_SIZE
// ballooning = spill -> revert.

#define N_Q   32768
#define K_CB  8192
#define D_DIM 256

typedef _Float16 half8 __attribute__((ext_vector_type(8)));
typedef float    f32x4 __attribute__((ext_vector_type(4)));

// Frag-major epk layout (half8 index):
//   epk: ((c16*8 + kk)*2 + hl)*64 + l
//        = e[c16*16 + (l&15)][kk*32 + (l>>4)*8 + j]   (*2^15, hi/lo)
// Matches mfma_f32_16x16x32_f16 A/B layout: row/col = lane&15,
// k = (lane>>4)*8 + j.

// ---------------- prep: codebook -> epk frag-major + cbs ----------------
// One block per c16 (16 codes); 512 blocks x 256 thr. Register-only.
__global__ __launch_bounds__(256)
void vq_prep_e(const float* __restrict__ cb, _Float16* __restrict__ epk,
               float* __restrict__ cbs) {
  const int t = threadIdx.x, c16 = blockIdx.x;

#pragma unroll
  for (int it = 0; it < 2; ++it) {
    const int s   = it * 256 + t;         // 0..511
    const int kk  = s >> 6, l = s & 63;
    const int row = c16 * 16 + (l & 15);
    const int k0  = kk * 32 + (l >> 4) * 8;
    const float4* ep = (const float4*)(cb + (size_t)row * 256 + k0);
    float4 a = ep[0], b = ep[1];
    float xs[8] = {a.x, a.y, a.z, a.w, b.x, b.y, b.z, b.w};
    half8 hh, ll;
#pragma unroll
    for (int j = 0; j < 8; ++j) {
      float x = xs[j] * 32768.0f;
      _Float16 hj = (_Float16)x;
      hh[j] = hj; ll[j] = (_Float16)(x - (float)hj);
    }
    half8* outg = (half8*)epk + (size_t)(c16 * 8 + kk) * 128;
    outg[l]      = hh;
    outg[64 + l] = ll;
  }

  // cbs: 16 codes x 16 threads; seg is the low 4 lane bits -> shfl group.
  {
    const int ci = t >> 4, seg = t & 15;
    const int row = c16 * 16 + ci;
    const float4* ep = (const float4*)(cb + (size_t)row * 256 + seg * 16);
    float s = 0.f;
#pragma unroll
    for (int u = 0; u < 4; ++u) {
      float4 v = ep[u];
      s = fmaf(v.x, v.x, fmaf(v.y, v.y, fmaf(v.z, v.z, fmaf(v.w, v.w, s))));
    }
#pragma unroll
    for (int off = 1; off < 16; off <<= 1) s += __shfl_xor(s, off);
    if (seg == 0) cbs[row] = s * 524288.0f;   // 2^19 * ||e||^2
  }
}

// ---------------- main: fused GEMM + running argmin ----------------
// Grid 256 blocks (1/CU: LDS 128KB). Block = 512 thr = 8 waves = 2/SIMD.
// Prologue converts this block's 128 z-rows f32 -> frag-major hi/lo A
// panel in LDS directly. Wave (h,v,p): rows h*64..+64, cols v*64..+64
// of ct = p*32+i for i in 0..32. No barriers in the main loop.

#define LOADB(KK, S)                                                  \
  do {                                                                \
    _Pragma("unroll")                                                 \
    for (int nt = 0; nt < 4; ++nt) {                                  \
      bh##S[nt] = ebi[nt * 1024 + (KK) * 128];                        \
      bl##S[nt] = ebi[nt * 1024 + (KK) * 128 + 64];                   \
    }                                                                 \
  } while (0)

#define LOADA(KK)                                                     \
  do {                                                                \
    _Pragma("unroll")                                                 \
    for (int mt = 0; mt < 4; ++mt) {                                  \
      ah[mt] = Ab[mt * 1024 + (KK) * 128];                            \
      al[mt] = Ab[mt * 1024 + (KK) * 128 + 64];                       \
    }                                                                 \
  } while (0)

#define MFMAS(S)                                                      \
  do {                                                                \
    _Pragma("unroll")                                                 \
    for (int mt = 0; mt < 4; ++mt) {                                  \
      _Pragma("unroll")                                               \
      for (int nt = 0; nt < 4; ++nt) {                                \
        acc[mt][nt] = __builtin_amdgcn_mfma_f32_16x16x32_f16(         \
            ah[mt], bh##S[nt], acc[mt][nt], 0, 0, 0);                 \
        acc[mt][nt] = __builtin_amdgcn_mfma_f32_16x16x32_f16(         \
            ah[mt], bl##S[nt], acc[mt][nt], 0, 0, 0);                 \
        acc[mt][nt] = __builtin_amdgcn_mfma_f32_16x16x32_f16(         \
            al[mt], bh##S[nt], acc[mt][nt], 0, 0, 0);                 \
      }                                                               \
    }                                                                 \
  } while (0)

__global__ __launch_bounds__(512, 2)
void vq_main(const float* __restrict__ z, const _Float16* __restrict__ epk,
             const float* __restrict__ cbs, int* __restrict__ out) {
  __shared__ __align__(16) char smem[131072];   // A panel, frag-major
  _Float16* const A = (_Float16*)smem;

  const int tid  = threadIdx.x;
  const int lane = tid & 63;
  const int w    = tid >> 6;       // 0..7
  const int h    = w >> 2;         // query-row half
  const int v    = w & 1;          // code-col half
  const int p    = (w >> 1) & 1;   // ct stream (0: cts 0..31, 1: 32..63)
  const int q    = lane & 15;
  const int quad = lane >> 4;
  const int qb   = blockIdx.x;
  const int q0   = qb * 128;

  // Prologue: z[q0..q0+128) f32 -> hi/lo f16 frag-major A (reg-only).
  // A half8 layout: [g*128 + hl*64 + l], g = q16*8 + kk. Per wave-iter:
  // g uniform, l = lane -> global reads = 16 rows x 128B lines; LDS
  // writes lane-linear 16B (conflict-free).
  {
    const float* zsrc = z + (size_t)q0 * 256;
#pragma unroll
    for (int it = 0; it < 8; ++it) {
      const int s   = it * 512 + tid;       // 0..4095
      const int g   = s >> 6, l = s & 63;   // g = q16*8 + kk
      const int row = (g >> 3) * 16 + (l & 15);
      const int k0  = (g & 7) * 32 + (l >> 4) * 8;
      const float4* zp = (const float4*)(zsrc + (size_t)row * 256 + k0);
      float4 a = zp[0], b = zp[1];
      float xs[8] = {a.x, a.y, a.z, a.w, b.x, b.y, b.z, b.w};
      half8 hh, ll;
#pragma unroll
      for (int j = 0; j < 8; ++j) {
        float x = xs[j] * 16.0f;
        _Float16 hj = (_Float16)x;
        hh[j] = hj; ll[j] = (_Float16)(x - (float)hj);
      }
      half8* const Ag = (half8*)A + g * 128;
      Ag[l]      = hh;
      Ag[64 + l] = ll;
    }
  }
  __syncthreads();   // A panel complete; read-only from here on

  // A frags (LDS, half8 units): Ab[mt*1024 + kk*128 (+64 for lo)]
  const half8* const Ab = (const half8*)A + h * 4096 + lane;
  // B frags (global, half8 units): ebi[nt*1024 + kk*128 (+64 for lo)]
  const half8* const eb = (const half8*)epk + (size_t)v * 4096 + lane;

  float    rd[16];
  unsigned rc[16];
#pragma unroll
  for (int i = 0; i < 16; ++i) { rd[i] = 3.0e38f; rc[i] = 0u; }

  for (int i = 0; i < 32; ++i) {
    const int ct   = p * 32 + i;
    const int col0 = ct * 128 + v * 64 + q;
    const half8* const ebi = eb + (size_t)ct * 8192;

    float cbsv[4];
#pragma unroll
    for (int nt = 0; nt < 4; ++nt) cbsv[nt] = cbs[col0 + nt * 16];

    f32x4 acc[4][4];
#pragma unroll
    for (int mt = 0; mt < 4; ++mt)
#pragma unroll
      for (int nt = 0; nt < 4; ++nt)
        acc[mt][nt] = (f32x4){0.f, 0.f, 0.f, 0.f};

    // B-prefetch pipeline: two named B sets (A/B), all indices
    // compile-time. LOADB(next) issues BEFORE the MFMA block, so the
    // L2 latency hides under 48 MFMAs. A reloaded per half-step.
    half8 bhA[4], blA[4], bhB[4], blB[4], ah[4], al[4];
    LOADB(0, A);
#pragma unroll
    for (int k2 = 0; k2 < 4; ++k2) {
      LOADB(2 * k2 + 1, B);
      LOADA(2 * k2);
      MFMAS(A);
      if (k2 < 3) LOADB(2 * k2 + 2, A);
      LOADA(2 * k2 + 1);
      MFMAS(B);
    }

    // dist = 2^19*cb_sq - 2*acc; running (min,idx). Ascending nt / i =>
    // strict < keeps the lowest index on ties.
#pragma unroll
    for (int mt = 0; mt < 4; ++mt)
#pragma unroll
      for (int r = 0; r < 4; ++r) {
        float d = fmaf(-2.0f, acc[mt][0][r], cbsv[0]);
        unsigned cidx = (unsigned)col0;
#pragma unroll
        for (int nt = 1; nt < 4; ++nt) {
          float dn = fmaf(-2.0f, acc[mt][nt][r], cbsv[nt]);
          if (dn < d) { d = dn; cidx = (unsigned)(col0 + nt * 16); }
        }
        int ri = mt * 4 + r;
        if (d < rd[ri]) { rd[ri] = d; rc[ri] = cidx; }
      }
  }

  // Reduce: 16-lane groups hold 16 cols of the same rows; then combine the
  // 4 (v,p) candidates per row via LDS (overlaying dead A region).
  __syncthreads();                       // all waves done reading A
  float*    const redD = (float*)smem;   // [4][128]
  unsigned* const redC = (unsigned*)(smem + 2048);

#pragma unroll
  for (int ri = 0; ri < 16; ++ri) {
    float d = rd[ri]; unsigned cidx = rc[ri];
#pragma unroll
    for (int off = 1; off < 16; off <<= 1) {
      float od = __shfl_xor(d, off);
      unsigned oc = __shfl_xor(cidx, off);
      if (od < d || (od == d && oc < cidx)) { d = od; cidx = oc; }
    }
    if (q == 0) {
      int row = h * 64 + (ri >> 2) * 16 + quad * 4 + (ri & 3);
      redD[(w & 3) * 128 + row] = d;
      redC[(w & 3) * 128 + row] = cidx;
    }
  }
  __syncthreads();
  if (tid < 128) {
    float d0 = redD[tid]; unsigned c0 = redC[tid];
#pragma unroll
    for (int s = 1; s < 4; ++s) {
      float ds = redD[s * 128 + tid]; unsigned cs = redC[s * 128 + tid];
      if (ds < d0 || (ds == d0 && cs < c0)) { d0 = ds; c0 = cs; }
    }
    out[q0 + tid] = (int)c0;
  }
}

extern "C" void kernel_launch(void* const* d_in, const int* in_sizes, int n_in,
                              void* d_out, int out_size, void* d_ws, size_t ws_size,
                              hipStream_t stream) {
  const float* z  = (const float*)d_in[0];   // [32,32,32,256] fp32
  const float* cb = (const float*)d_in[1];   // [8192,256] fp32
  char* ws = (char*)d_ws;
  // ws layout: epk 8.4M (frag-major cb hi/lo) | cbs 32K @ +16M
  _Float16* epk = (_Float16*)(ws);
  float*    cbs = (float*)(ws + (size_t)16 * 1024 * 1024);

  hipLaunchKernelGGL(vq_prep_e, dim3(512), dim3(256), 0, stream, cb, epk, cbs);
  hipLaunchKernelGGL(vq_main,   dim3(256), dim3(512), 0, stream,
                     z, epk, cbs, (int*)d_out);
}